// Round 6
// baseline (2555.518 us; speedup 1.0000x reference)
//
#include <hip/hip_runtime.h>
#include <math.h>

typedef float f4u __attribute__((ext_vector_type(4), aligned(4)));
typedef float nfloat4 __attribute__((ext_vector_type(4), aligned(16)));

__device__ __forceinline__ float softsign(float v) {
    float d = 1.0f + fabsf(v);
    return v * __builtin_amdgcn_rcpf(d);
}
__device__ __forceinline__ void nt_store4(float* p, float a, float b, float c, float d) {
    nfloat4 v; v.x = a; v.y = b; v.z = c; v.w = d;
    __builtin_nontemporal_store(v, (nfloat4*)p);
}
__device__ __forceinline__ int clamp63(int v) { return v < 0 ? 0 : (v > 63 ? 63 : v); }

__device__ __forceinline__ void load_row6(const float* __restrict__ row, int x0, float r[6]) {
    const float4 v = *(const float4*)(row + x0);
    r[0] = row[x0 == 0 ? 0 : x0 - 1];
    r[1] = v.x; r[2] = v.y; r[3] = v.z; r[4] = v.w;
    r[5] = row[x0 == 60 ? 63 : x0 + 4];
}

// -------- first layer: 2 input channels -> 1 channel --------
__global__ __launch_bounds__(256) void conv_first(const float* __restrict__ in0,
                                                  const float* __restrict__ in1,
                                                  float* __restrict__ out,
                                                  const float* __restrict__ w,
                                                  const float* __restrict__ bias) {
    int tid = blockIdx.x * 256 + threadIdx.x;
    int xq = (tid & 15) << 2;
    int y  = (tid >> 4) & 63;
    int z0 = ((tid >> 10) & 15) << 2;
    int b  = tid >> 14;
    const float* base0 = in0 + (size_t)b * 262144;
    const float* base1 = in1 + (size_t)b * 262144;

    float acc[4][4];
    #pragma unroll
    for (int i = 0; i < 4; ++i)
        #pragma unroll
        for (int j = 0; j < 4; ++j) acc[i][j] = 0.0f;

    #pragma unroll
    for (int zi = 0; zi < 6; ++zi) {
        int zin = clamp63(z0 + zi - 1);
        const float* p0 = base0 + zin * 4096;
        const float* p1 = base1 + zin * 4096;
        #pragma unroll
        for (int dy = 0; dy < 3; ++dy) {
            int yin = clamp63(y + dy - 1);
            float r0[6], r1[6];
            load_row6(p0 + yin * 64, xq, r0);
            load_row6(p1 + yin * 64, xq, r1);
            #pragma unroll
            for (int dz = 0; dz < 3; ++dz) {
                int zo = zi - dz;
                if (zo >= 0 && zo < 4) {
                    #pragma unroll
                    for (int dx = 0; dx < 3; ++dx) {
                        float w0v = w[dz * 9 + dy * 3 + dx];
                        float w1v = w[27 + dz * 9 + dy * 3 + dx];
                        #pragma unroll
                        for (int xx = 0; xx < 4; ++xx) {
                            acc[zo][xx] = fmaf(w0v, r0[xx + dx], acc[zo][xx]);
                            acc[zo][xx] = fmaf(w1v, r1[xx + dx], acc[zo][xx]);
                        }
                    }
                }
            }
        }
    }
    float bv = *bias;
    float* obase = out + (size_t)b * 262144 + (size_t)z0 * 4096 + y * 64 + xq;
    #pragma unroll
    for (int zo = 0; zo < 4; ++zo) {
        nt_store4(obase + zo * 4096,
                  softsign(acc[zo][0] + bv), softsign(acc[zo][1] + bv),
                  softsign(acc[zo][2] + bv), softsign(acc[zo][3] + bv));
    }
}

// -------- fused pair of middle layers: in -> (conv,softsign) -> (conv,softsign) -> out --------
// Output tile per block: 64x * 16y * 2z.  2048 blocks.
// LDS A: staged input, 6 planes (z0-2..z0+3 clamped) * 20 rows (y0-2..y0+17 clamped),
//        idx = x+2 for x in [-2,65] (edge-clamped values), stride 76 (bank-conflict-free).
// LDS B: intermediate incl. halo, 4 planes (rz=z0-1+pz, value = inter(clamp(rz))) *
//        18 rows (ry=y0-1+p, value = inter(clamp(ry))), idx = x+1 for x in [-1,64], stride 76.
// Fusion boundary rule: the reference edge-pads the INTERMEDIATE, so halo entries of B must
// DUPLICATE boundary values of inter, not evaluate the conv outside the domain. Achieved by
// evaluating layer 1 at clamped coordinates (ys=clamp(ry), zs=clamp(rz)) and duplicating x edges.
#define AROW 76
#define APLANE (20 * AROW)
#define BROW 76
#define BPLANE (18 * BROW)

__global__ __launch_bounds__(256) void conv_mid2(const float* __restrict__ in,
                                                 float* __restrict__ out,
                                                 const float* __restrict__ w1p,
                                                 const float* __restrict__ b1p,
                                                 const float* __restrict__ w2p,
                                                 const float* __restrict__ b2p) {
    __shared__ float A[6 * APLANE];
    __shared__ float B[4 * BPLANE];

    int blk = blockIdx.x;
    int y0 = (blk & 3) << 4;            // 0,16,32,48
    int z0 = ((blk >> 2) & 31) << 1;    // 0..62 step 2
    int b  = blk >> 7;                  // 0..15
    int t  = threadIdx.x;
    int l  = t & 15;
    int g  = t >> 4;

    const float* base = in + (size_t)b * 262144;

    // ---- stage 120 rows (6 planes x 20 rows) ----
    #pragma unroll
    for (int it = 0; it < 8; ++it) {
        int rid = it * 16 + g;
        if (rid < 120) {
            int pa = rid / 20;
            int pr = rid - pa * 20;
            int gz = clamp63(z0 - 2 + pa);
            int gy = clamp63(y0 - 2 + pr);
            const float* grow = base + gz * 4096 + gy * 64;
            float* lrow = &A[pa * APLANE + pr * AROW];
            if (l == 0) {
                float2 v = *(const float2*)grow;                 // in[0], in[1]
                lrow[0] = v.x; lrow[1] = v.x; lrow[2] = v.x; lrow[3] = v.y;
            } else {
                f4u v = *(const f4u*)(grow + 4 * l - 2);          // x = 4l-2 .. 4l+1
                *(float4*)(lrow + 4 * l) = (float4){v.x, v.y, v.z, v.w};
            }
            if (l == 15) {
                float2 v = *(const float2*)(grow + 62);           // in[62], in[63]
                lrow[64] = v.x; lrow[65] = v.y; lrow[66] = v.y; lrow[67] = v.y;
            }
        }
    }

    float w1[27];
    #pragma unroll
    for (int i = 0; i < 27; ++i) w1[i] = w1p[i];
    float b1 = *b1p;

    __syncthreads();

    // ---- layer 1: compute B (4 planes x 18 rows x x[-1..64]) ----
    #pragma unroll
    for (int pass = 0; pass < 2; ++pass) {
        int p = pass ? (16 + g) : g;
        if (pass == 0 || g < 2) {
            int ys  = clamp63(y0 - 1 + p);
            int prb = ys - y0 + 1;      // input row base: taps at prb+dy, dy=0..2
            float tp[3][3][8];          // [dz][dy][j], j <-> A idx 4l+j <-> x = 4l-2+j
            float vo[4] = {0.f, 0.f, 0.f, 0.f};
            int zs_prev = -1;
            #pragma unroll
            for (int pz = 0; pz < 4; ++pz) {
                int zs = clamp63(z0 - 1 + pz);
                if (zs != zs_prev) {
                    if (pz == 0) {
                        #pragma unroll
                        for (int dz = 0; dz < 3; ++dz) {
                            int pa = zs - z0 + 1 + dz;
                            #pragma unroll
                            for (int dy = 0; dy < 3; ++dy) {
                                const float* r = &A[pa * APLANE + (prb + dy) * AROW + 4 * l];
                                float4 v0 = *(const float4*)r;
                                float4 v1 = *(const float4*)(r + 4);
                                tp[dz][dy][0] = v0.x; tp[dz][dy][1] = v0.y;
                                tp[dz][dy][2] = v0.z; tp[dz][dy][3] = v0.w;
                                tp[dz][dy][4] = v1.x; tp[dz][dy][5] = v1.y;
                                tp[dz][dy][6] = v1.z; tp[dz][dy][7] = v1.w;
                            }
                        }
                    } else {
                        #pragma unroll
                        for (int dy = 0; dy < 3; ++dy)
                            #pragma unroll
                            for (int j = 0; j < 8; ++j) {
                                tp[0][dy][j] = tp[1][dy][j];
                                tp[1][dy][j] = tp[2][dy][j];
                            }
                        int pa = zs - z0 + 3;
                        #pragma unroll
                        for (int dy = 0; dy < 3; ++dy) {
                            const float* r = &A[pa * APLANE + (prb + dy) * AROW + 4 * l];
                            float4 v0 = *(const float4*)r;
                            float4 v1 = *(const float4*)(r + 4);
                            tp[2][dy][0] = v0.x; tp[2][dy][1] = v0.y;
                            tp[2][dy][2] = v0.z; tp[2][dy][3] = v0.w;
                            tp[2][dy][4] = v1.x; tp[2][dy][5] = v1.y;
                            tp[2][dy][6] = v1.z; tp[2][dy][7] = v1.w;
                        }
                    }
                    float s[4] = {0.f, 0.f, 0.f, 0.f};
                    #pragma unroll
                    for (int dz = 0; dz < 3; ++dz)
                        #pragma unroll
                        for (int dy = 0; dy < 3; ++dy)
                            #pragma unroll
                            for (int dx = 0; dx < 3; ++dx) {
                                float wv = w1[dz * 9 + dy * 3 + dx];
                                #pragma unroll
                                for (int xx = 0; xx < 4; ++xx)
                                    s[xx] = fmaf(wv, tp[dz][dy][xx + dx + 1], s[xx]);
                            }
                    #pragma unroll
                    for (int xx = 0; xx < 4; ++xx) vo[xx] = softsign(s[xx] + b1);
                }
                // write inter values for xs = 4l..4l+3 at B idx = xs+1
                float* br = &B[pz * BPLANE + p * BROW];
                br[4 * l + 1] = vo[0];
                *(float2*)(br + 4 * l + 2) = (float2){vo[1], vo[2]};
                br[4 * l + 4] = vo[3];
                if (l == 0)  br[0]  = vo[0];   // x=-1 dup of x=0
                if (l == 15) br[65] = vo[3];   // x=64 dup of x=63
                zs_prev = zs;
            }
        }
    }

    float w2[27];
    #pragma unroll
    for (int i = 0; i < 27; ++i) w2[i] = w2p[i];
    float b2 = *b2p;

    __syncthreads();

    // ---- layer 2: 2z x 1y x 4x per thread from B ----
    float acc[2][4];
    #pragma unroll
    for (int i = 0; i < 2; ++i)
        #pragma unroll
        for (int j = 0; j < 4; ++j) acc[i][j] = 0.0f;

    #pragma unroll
    for (int pz = 0; pz < 4; ++pz) {
        #pragma unroll
        for (int dy = 0; dy < 3; ++dy) {
            const float* br = &B[pz * BPLANE + (g + dy) * BROW + 4 * l];
            float4 v  = *(const float4*)br;        // idx 4l..4l+3  = x 4l-1..4l+2
            float2 v2 = *(const float2*)(br + 4);  // idx 4l+4,4l+5 = x 4l+3,4l+4
            float r[6] = {v.x, v.y, v.z, v.w, v2.x, v2.y};
            #pragma unroll
            for (int dz = 0; dz < 3; ++dz) {
                int zo = pz - dz;
                if (zo >= 0 && zo < 2) {
                    #pragma unroll
                    for (int dx = 0; dx < 3; ++dx) {
                        float wv = w2[dz * 9 + dy * 3 + dx];
                        #pragma unroll
                        for (int xx = 0; xx < 4; ++xx)
                            acc[zo][xx] = fmaf(wv, r[xx + dx], acc[zo][xx]);
                    }
                }
            }
        }
    }

    int y = y0 + g;
    float* obase = out + (size_t)b * 262144 + (size_t)z0 * 4096 + y * 64 + 4 * l;
    #pragma unroll
    for (int zo = 0; zo < 2; ++zo) {
        nt_store4(obase + zo * 4096,
                  softsign(acc[zo][0] + b2), softsign(acc[zo][1] + b2),
                  softsign(acc[zo][2] + b2), softsign(acc[zo][3] + b2));
    }
}

// -------- last layer: 1 -> 3 channels + strided downsample outputs --------
__global__ __launch_bounds__(256) void conv_last(const float* __restrict__ in,
                                                 float* __restrict__ out,
                                                 const float* __restrict__ w,
                                                 const float* __restrict__ bias) {
    int tid = blockIdx.x * 256 + threadIdx.x;
    int xq = (tid & 15) << 2;
    int y  = (tid >> 4) & 63;
    int z0 = ((tid >> 10) & 15) << 2;
    int b  = tid >> 14;
    const float* base = in + (size_t)b * 262144;

    float acc[4][3][4];
    #pragma unroll
    for (int i = 0; i < 4; ++i)
        #pragma unroll
        for (int c = 0; c < 3; ++c)
            #pragma unroll
            for (int j = 0; j < 4; ++j) acc[i][c][j] = 0.0f;

    #pragma unroll
    for (int zi = 0; zi < 6; ++zi) {
        int zin = clamp63(z0 + zi - 1);
        const float* plane = base + zin * 4096;
        #pragma unroll
        for (int dy = 0; dy < 3; ++dy) {
            int yin = clamp63(y + dy - 1);
            float r[6];
            load_row6(plane + yin * 64, xq, r);
            #pragma unroll
            for (int dz = 0; dz < 3; ++dz) {
                int zo = zi - dz;
                if (zo >= 0 && zo < 4) {
                    #pragma unroll
                    for (int c = 0; c < 3; ++c) {
                        #pragma unroll
                        for (int dx = 0; dx < 3; ++dx) {
                            float wv = w[c * 27 + dz * 9 + dy * 3 + dx];
                            #pragma unroll
                            for (int xx = 0; xx < 4; ++xx)
                                acc[zo][c][xx] = fmaf(wv, r[xx + dx], acc[zo][c][xx]);
                        }
                    }
                }
            }
        }
    }

    float* r64 = out;
    float* r32 = out + 12582912;
    float* r16 = r32 + 1572864;
    float* r8  = r16 + 196608;

    float vals[4][3][4];
    #pragma unroll
    for (int zo = 0; zo < 4; ++zo)
        #pragma unroll
        for (int c = 0; c < 3; ++c) {
            float bv = bias[c];
            #pragma unroll
            for (int xx = 0; xx < 4; ++xx)
                vals[zo][c][xx] = softsign(acc[zo][c][xx] + bv);
        }

    #pragma unroll
    for (int c = 0; c < 3; ++c) {
        float* cb = r64 + ((size_t)b * 3 + c) * 262144 + (size_t)z0 * 4096 + y * 64 + xq;
        #pragma unroll
        for (int zo = 0; zo < 4; ++zo) {
            nt_store4(cb + zo * 4096,
                      vals[zo][c][0], vals[zo][c][1], vals[zo][c][2], vals[zo][c][3]);
        }
    }
    if ((y & 1) == 0) {
        #pragma unroll
        for (int c = 0; c < 3; ++c) {
            size_t cb = ((size_t)b * 3 + c) * 32768 + (size_t)(y >> 1) * 32;
            #pragma unroll
            for (int zo = 0; zo < 4; zo += 2) {
                size_t zb = cb + (size_t)((z0 + zo) >> 1) * 1024;
                __builtin_nontemporal_store(vals[zo][c][0], r32 + zb + ((xq + 0) >> 1));
                __builtin_nontemporal_store(vals[zo][c][2], r32 + zb + ((xq + 2) >> 1));
            }
        }
    }
    if ((y & 3) == 0) {
        #pragma unroll
        for (int c = 0; c < 3; ++c) {
            __builtin_nontemporal_store(vals[0][c][0],
                r16 + ((size_t)b * 3 + c) * 4096 + (size_t)(z0 >> 2) * 256 + (y >> 2) * 16 + (xq >> 2));
        }
    }
    if ((y & 7) == 0 && (z0 & 7) == 0 && (xq & 7) == 0) {
        #pragma unroll
        for (int c = 0; c < 3; ++c) {
            __builtin_nontemporal_store(vals[0][c][0],
                r8 + ((size_t)b * 3 + c) * 512 + (size_t)(z0 >> 3) * 64 + (y >> 3) * 8 + (xq >> 3));
        }
    }
}

extern "C" void kernel_launch(void* const* d_in, const int* in_sizes, int n_in,
                              void* d_out, int out_size, void* d_ws, size_t ws_size,
                              hipStream_t stream) {
    const float* preop = (const float*)d_in[0];
    const float* intra = (const float*)d_in[1];
    const float* w0    = (const float*)d_in[2];
    const float* b0    = (const float*)d_in[3];
    const float* ws    = (const float*)d_in[4];
    const float* bs    = (const float*)d_in[5];
    const float* wX    = (const float*)d_in[6];
    const float* bX    = (const float*)d_in[7];
    float* out = (float*)d_out;

    float* buf0 = (float*)d_ws;
    float* buf1 = out;

    conv_first<<<dim3(1024), dim3(256), 0, stream>>>(preop, intra, buf0, w0, b0);
    for (int k = 0; k < 50; ++k) {
        const float* src = (k & 1) ? buf1 : buf0;
        float* dst       = (k & 1) ? buf0 : buf1;
        conv_mid2<<<dim3(2048), dim3(256), 0, stream>>>(src, dst,
                                                        ws + (2 * k) * 27, bs + 2 * k,
                                                        ws + (2 * k + 1) * 27, bs + 2 * k + 1);
    }
    // k=49 (odd) wrote buf0 -> final layer reads buf0
    conv_last<<<dim3(1024), dim3(256), 0, stream>>>(buf0, out, wX, bX);
}

// Round 7
// 1511.555 us; speedup vs baseline: 1.6907x; 1.6907x over previous
//
#include <hip/hip_runtime.h>
#include <math.h>

typedef float f4u __attribute__((ext_vector_type(4), aligned(4)));
typedef float nfloat4 __attribute__((ext_vector_type(4), aligned(16)));

__device__ __forceinline__ float softsign(float v) {
    float d = 1.0f + fabsf(v);
    return v * __builtin_amdgcn_rcpf(d);
}
__device__ __forceinline__ void nt_store4(float* p, float a, float b, float c, float d) {
    nfloat4 v; v.x = a; v.y = b; v.z = c; v.w = d;
    __builtin_nontemporal_store(v, (nfloat4*)p);
}
__device__ __forceinline__ int clamp63(int v) { return v < 0 ? 0 : (v > 63 ? 63 : v); }

__device__ __forceinline__ void load_row6(const float* __restrict__ row, int x0, float r[6]) {
    const float4 v = *(const float4*)(row + x0);
    r[0] = row[x0 == 0 ? 0 : x0 - 1];
    r[1] = v.x; r[2] = v.y; r[3] = v.z; r[4] = v.w;
    r[5] = row[x0 == 60 ? 63 : x0 + 4];
}

// -------- first layer: 2 input channels -> 1 channel --------
__global__ __launch_bounds__(256) void conv_first(const float* __restrict__ in0,
                                                  const float* __restrict__ in1,
                                                  float* __restrict__ out,
                                                  const float* __restrict__ w,
                                                  const float* __restrict__ bias) {
    int tid = blockIdx.x * 256 + threadIdx.x;
    int xq = (tid & 15) << 2;
    int y  = (tid >> 4) & 63;
    int z0 = ((tid >> 10) & 15) << 2;
    int b  = tid >> 14;
    const float* base0 = in0 + (size_t)b * 262144;
    const float* base1 = in1 + (size_t)b * 262144;

    float acc[4][4];
    #pragma unroll
    for (int i = 0; i < 4; ++i)
        #pragma unroll
        for (int j = 0; j < 4; ++j) acc[i][j] = 0.0f;

    #pragma unroll
    for (int zi = 0; zi < 6; ++zi) {
        int zin = clamp63(z0 + zi - 1);
        const float* p0 = base0 + zin * 4096;
        const float* p1 = base1 + zin * 4096;
        #pragma unroll
        for (int dy = 0; dy < 3; ++dy) {
            int yin = clamp63(y + dy - 1);
            float r0[6], r1[6];
            load_row6(p0 + yin * 64, xq, r0);
            load_row6(p1 + yin * 64, xq, r1);
            #pragma unroll
            for (int dz = 0; dz < 3; ++dz) {
                int zo = zi - dz;
                if (zo >= 0 && zo < 4) {
                    #pragma unroll
                    for (int dx = 0; dx < 3; ++dx) {
                        float w0v = w[dz * 9 + dy * 3 + dx];
                        float w1v = w[27 + dz * 9 + dy * 3 + dx];
                        #pragma unroll
                        for (int xx = 0; xx < 4; ++xx) {
                            acc[zo][xx] = fmaf(w0v, r0[xx + dx], acc[zo][xx]);
                            acc[zo][xx] = fmaf(w1v, r1[xx + dx], acc[zo][xx]);
                        }
                    }
                }
            }
        }
    }
    float bv = *bias;
    float* obase = out + (size_t)b * 262144 + (size_t)z0 * 4096 + y * 64 + xq;
    #pragma unroll
    for (int zo = 0; zo < 4; ++zo) {
        float4 o;
        o.x = softsign(acc[zo][0] + bv);
        o.y = softsign(acc[zo][1] + bv);
        o.z = softsign(acc[zo][2] + bv);
        o.w = softsign(acc[zo][3] + bv);
        *(float4*)(obase + zo * 4096) = o;   // normal store: keep in LLC for next layer
    }
}

// -------- middle layers: LDS-staged, block computes 64x * 8y * 4z --------
// Grid 2048 -> 8 blocks/CU.  LDS: 6 planes x 10 rows x stride 68 = 16.3 KB.
// Row layout idx = x+1: [0]=clamp(x-1), [1..64]=x0..63, [65]=clamp(x64).
#define LROW   68
#define LPLANE 680   // 10*68

__global__ __launch_bounds__(256) void conv_mid(const float* __restrict__ in,
                                                float* __restrict__ out,
                                                const float* __restrict__ w,   // 27
                                                const float* __restrict__ bias) {
    __shared__ float lds[6 * LPLANE];

    int blk = blockIdx.x;
    int y0 = (blk & 7) << 3;           // 0..56 step 8
    int z0 = ((blk >> 3) & 15) << 2;   // 0..60 step 4
    int b  = blk >> 7;                 // 0..15
    int t  = threadIdx.x;
    int l  = t & 15;
    int g  = t >> 4;

    const float* base = in + (size_t)b * 262144;

    // preload weights (uniform) while staging is in flight
    float wv[27];
    #pragma unroll
    for (int i = 0; i < 27; ++i) wv[i] = w[i];
    float bv = *bias;

    // ---- stage 60 rows (6 z-planes x 10 y-rows) ----
    #pragma unroll
    for (int it = 0; it < 4; ++it) {
        int rid = it * 16 + g;
        if (rid < 60) {
            int pa = rid / 10;
            int pr = rid - pa * 10;
            int gz = clamp63(z0 - 1 + pa);
            int gy = clamp63(y0 - 1 + pr);
            const float* grow = base + gz * 4096 + gy * 64;
            float* lrow = &lds[pa * LPLANE + pr * LROW];
            if (l == 0) {
                float4 v = *(const float4*)grow;
                float4 o; o.x = v.x; o.y = v.x; o.z = v.y; o.w = v.z;  // clamp(x-1),x0,x1,x2
                *(float4*)lrow = o;
            } else {
                f4u v = *(const f4u*)(grow + 4 * l - 1);               // x(4l-1)..x(4l+2)
                *(float4*)(lrow + 4 * l) = (float4){v.x, v.y, v.z, v.w};
            }
            if (l == 15) {
                float t63 = grow[63];
                *(float2*)(lrow + 64) = (float2){t63, t63};            // x63, clamp(x64)
            }
        }
    }
    __syncthreads();

    // ---- compute: thread = 2z x 1y x 4x ----
    int xq   = l << 2;
    int yloc = g & 7;     // 0..7
    int zh   = g >> 3;    // 0..1: output z = z0 + 2*zh + {0,1}

    float acc[2][4];
    #pragma unroll
    for (int i = 0; i < 2; ++i)
        #pragma unroll
        for (int j = 0; j < 4; ++j) acc[i][j] = 0.0f;

    #pragma unroll
    for (int zi = 0; zi < 4; ++zi) {               // staged plane 2*zh + zi
        const float* pl = &lds[(2 * zh + zi) * LPLANE];
        #pragma unroll
        for (int dy = 0; dy < 3; ++dy) {
            const float* lrow = pl + (yloc + dy) * LROW;
            const float4 v  = *(const float4*)(lrow + xq);
            const float2 v2 = *(const float2*)(lrow + xq + 4);
            float r[6] = {v.x, v.y, v.z, v.w, v2.x, v2.y};
            #pragma unroll
            for (int dz = 0; dz < 3; ++dz) {
                int zo = zi - dz;
                if (zo >= 0 && zo < 2) {
                    #pragma unroll
                    for (int dx = 0; dx < 3; ++dx) {
                        float ww = wv[dz * 9 + dy * 3 + dx];
                        #pragma unroll
                        for (int xx = 0; xx < 4; ++xx)
                            acc[zo][xx] = fmaf(ww, r[xx + dx], acc[zo][xx]);
                    }
                }
            }
        }
    }

    int y = y0 + yloc;
    float* obase = out + (size_t)b * 262144 + (size_t)(z0 + 2 * zh) * 4096 + y * 64 + xq;
    #pragma unroll
    for (int zo = 0; zo < 2; ++zo) {
        float4 o;
        o.x = softsign(acc[zo][0] + bv);
        o.y = softsign(acc[zo][1] + bv);
        o.z = softsign(acc[zo][2] + bv);
        o.w = softsign(acc[zo][3] + bv);
        *(float4*)(obase + zo * 4096) = o;   // normal store: LLC-resident ping-pong
    }
}

// -------- last layer: 1 -> 3 channels + strided downsample outputs --------
__global__ __launch_bounds__(256) void conv_last(const float* __restrict__ in,
                                                 float* __restrict__ out,
                                                 const float* __restrict__ w,
                                                 const float* __restrict__ bias) {
    int tid = blockIdx.x * 256 + threadIdx.x;
    int xq = (tid & 15) << 2;
    int y  = (tid >> 4) & 63;
    int z0 = ((tid >> 10) & 15) << 2;
    int b  = tid >> 14;
    const float* base = in + (size_t)b * 262144;

    float acc[4][3][4];
    #pragma unroll
    for (int i = 0; i < 4; ++i)
        #pragma unroll
        for (int c = 0; c < 3; ++c)
            #pragma unroll
            for (int j = 0; j < 4; ++j) acc[i][c][j] = 0.0f;

    #pragma unroll
    for (int zi = 0; zi < 6; ++zi) {
        int zin = clamp63(z0 + zi - 1);
        const float* plane = base + zin * 4096;
        #pragma unroll
        for (int dy = 0; dy < 3; ++dy) {
            int yin = clamp63(y + dy - 1);
            float r[6];
            load_row6(plane + yin * 64, xq, r);
            #pragma unroll
            for (int dz = 0; dz < 3; ++dz) {
                int zo = zi - dz;
                if (zo >= 0 && zo < 4) {
                    #pragma unroll
                    for (int c = 0; c < 3; ++c) {
                        #pragma unroll
                        for (int dx = 0; dx < 3; ++dx) {
                            float wc = w[c * 27 + dz * 9 + dy * 3 + dx];
                            #pragma unroll
                            for (int xx = 0; xx < 4; ++xx)
                                acc[zo][c][xx] = fmaf(wc, r[xx + dx], acc[zo][c][xx]);
                        }
                    }
                }
            }
        }
    }

    float* r64 = out;
    float* r32 = out + 12582912;
    float* r16 = r32 + 1572864;
    float* r8  = r16 + 196608;

    float vals[4][3][4];
    #pragma unroll
    for (int zo = 0; zo < 4; ++zo)
        #pragma unroll
        for (int c = 0; c < 3; ++c) {
            float bv = bias[c];
            #pragma unroll
            for (int xx = 0; xx < 4; ++xx)
                vals[zo][c][xx] = softsign(acc[zo][c][xx] + bv);
        }

    #pragma unroll
    for (int c = 0; c < 3; ++c) {
        float* cb = r64 + ((size_t)b * 3 + c) * 262144 + (size_t)z0 * 4096 + y * 64 + xq;
        #pragma unroll
        for (int zo = 0; zo < 4; ++zo) {
            nt_store4(cb + zo * 4096,
                      vals[zo][c][0], vals[zo][c][1], vals[zo][c][2], vals[zo][c][3]);
        }
    }
    if ((y & 1) == 0) {
        #pragma unroll
        for (int c = 0; c < 3; ++c) {
            size_t cb = ((size_t)b * 3 + c) * 32768 + (size_t)(y >> 1) * 32;
            #pragma unroll
            for (int zo = 0; zo < 4; zo += 2) {
                size_t zb = cb + (size_t)((z0 + zo) >> 1) * 1024;
                __builtin_nontemporal_store(vals[zo][c][0], r32 + zb + ((xq + 0) >> 1));
                __builtin_nontemporal_store(vals[zo][c][2], r32 + zb + ((xq + 2) >> 1));
            }
        }
    }
    if ((y & 3) == 0) {
        #pragma unroll
        for (int c = 0; c < 3; ++c) {
            __builtin_nontemporal_store(vals[0][c][0],
                r16 + ((size_t)b * 3 + c) * 4096 + (size_t)(z0 >> 2) * 256 + (y >> 2) * 16 + (xq >> 2));
        }
    }
    if ((y & 7) == 0 && (z0 & 7) == 0 && (xq & 7) == 0) {
        #pragma unroll
        for (int c = 0; c < 3; ++c) {
            __builtin_nontemporal_store(vals[0][c][0],
                r8 + ((size_t)b * 3 + c) * 512 + (size_t)(z0 >> 3) * 64 + (y >> 3) * 8 + (xq >> 3));
        }
    }
}

extern "C" void kernel_launch(void* const* d_in, const int* in_sizes, int n_in,
                              void* d_out, int out_size, void* d_ws, size_t ws_size,
                              hipStream_t stream) {
    const float* preop = (const float*)d_in[0];
    const float* intra = (const float*)d_in[1];
    const float* w0    = (const float*)d_in[2];
    const float* b0    = (const float*)d_in[3];
    const float* ws    = (const float*)d_in[4];
    const float* bs    = (const float*)d_in[5];
    const float* wX    = (const float*)d_in[6];
    const float* bX    = (const float*)d_in[7];
    float* out = (float*)d_out;

    float* buf0 = (float*)d_ws;
    float* buf1 = out;

    conv_first<<<dim3(1024), dim3(256), 0, stream>>>(preop, intra, buf0, w0, b0);
    for (int i = 0; i < 100; ++i) {
        const float* src = (i & 1) ? buf1 : buf0;
        float* dst       = (i & 1) ? buf0 : buf1;
        conv_mid<<<dim3(2048), dim3(256), 0, stream>>>(src, dst, ws + i * 27, bs + i);
    }
    conv_last<<<dim3(1024), dim3(256), 0, stream>>>(buf0, out, wX, bX);
}